// Round 9
// baseline (269.859 us; speedup 1.0000x reference)
//
#include <hip/hip_runtime.h>
#include <math.h>

#define NNODES 50000
#define INF    256
#define OUTF   64
#define NEDGES 800000
#define NCHUNK 196            // ceil(50000/256)
#define CVTBLK 128            // blocks doing weight conversion in fused K1
#define HISTBLK ((NEDGES + 1023) / 1024)   // 782: 1024 edges/block, 4/thread
#define CSTRIDE 16            // one counter per 64B cacheline

typedef __attribute__((ext_vector_type(8))) short bf16x8;
typedef __attribute__((ext_vector_type(4))) float f32x4;

__device__ __forceinline__ unsigned short f2bf(float x) {
    unsigned int b = __float_as_uint(x);
    unsigned int r = b + 0x7FFF + ((b >> 16) & 1);   // RNE
    return (unsigned short)(r >> 16);
}

__device__ __forceinline__ unsigned int pack2bf(float lo, float hi) {
    return (unsigned int)f2bf(lo) | ((unsigned int)f2bf(hi) << 16);
}

// ---------------------------------------------------------------------------
// K1 (fused): blocks 0..127 transpose+convert weights; blocks 128..: dst
// histogram with line-strided counters, capturing each edge's RANK.
// ---------------------------------------------------------------------------
__global__ __launch_bounds__(256) void convert_hist(
    const float* __restrict__ Wm, const float* __restrict__ Ws,
    unsigned short* __restrict__ BtG,
    const int* __restrict__ edst, int* __restrict__ cntS,
    int* __restrict__ rank)
{
    if (blockIdx.x < CVTBLK) {
        int n = blockIdx.x;          // 0..127
        int k = threadIdx.x;         // 0..255
        float val = (n < 64) ? Wm[(size_t)k * OUTF + n]
                             : Ws[(size_t)k * OUTF + (n - 64)];
        BtG[(size_t)n * INF + k] = f2bf(val);
    } else {
        int base = (blockIdx.x - CVTBLK) * 1024 + threadIdx.x;
        int d[4];
        bool ok[4];
        #pragma unroll
        for (int j = 0; j < 4; ++j) {
            int e = base + j * 256;
            ok[j] = (e < NEDGES);
            d[j]  = ok[j] ? edst[e] : 0;
        }
        int r[4];
        #pragma unroll
        for (int j = 0; j < 4; ++j)
            r[j] = ok[j] ? atomicAdd(&cntS[(size_t)d[j] * CSTRIDE], 1) : 0;
        #pragma unroll
        for (int j = 0; j < 4; ++j)
            if (ok[j]) rank[base + j * 256] = r[j];
    }
}

// ---------------------------------------------------------------------------
// K-GEMM: barrier-free, LDS-free bf16 MFMA dual-GEMM + activation epilogue.
// Wave = 16 rows x 128 cols. A frags loaded directly from global fp32
// (one dwordx4 pair covers 16 rows x 64B fully-used lines), converted
// inline to bf16. B frags re-read per K-tile from BtG (64 KB, L2-resident).
// No LDS, no __syncthreads.
// ---------------------------------------------------------------------------
__global__ __launch_bounds__(256, 3) void gemm_mfma(
    const float* __restrict__ feat,
    const unsigned short* __restrict__ BtG,
    unsigned int* __restrict__ uv,
    int n_nodes)
{
    const int tid  = threadIdx.x;
    const int w    = tid >> 6;
    const int lane = tid & 63;
    const int quad = lane >> 4;
    const int col  = lane & 15;
    const int mw   = blockIdx.x * 64 + w * 16;   // wave's first row

    int mrow = mw + col;
    if (mrow >= n_nodes) mrow = n_nodes - 1;     // clamp; epilogue guards
    const float* arow = feat + (size_t)mrow * INF + quad * 8;

    f32x4 acc[8];
    #pragma unroll
    for (int c = 0; c < 8; ++c) acc[c] = (f32x4){0.f, 0.f, 0.f, 0.f};

    #pragma unroll
    for (int t = 0; t < 8; ++t) {
        const int kb = t * 32;
        float4 a0 = *(const float4*)(arow + kb);
        float4 a1 = *(const float4*)(arow + kb + 4);
        union { unsigned int u[4]; bf16x8 v; } af;
        af.u[0] = pack2bf(a0.x, a0.y);
        af.u[1] = pack2bf(a0.z, a0.w);
        af.u[2] = pack2bf(a1.x, a1.y);
        af.u[3] = pack2bf(a1.z, a1.w);

        #pragma unroll
        for (int c = 0; c < 8; ++c) {
            bf16x8 bf = *(const bf16x8*)&BtG[(size_t)(16 * c + col) * INF + kb + quad * 8];
            acc[c] = __builtin_amdgcn_mfma_f32_16x16x32_bf16(af.v, bf, acc[c], 0, 0, 0);
        }
    }

    // ---- epilogue: activations, pack bf16 u|v ----
    const int mbase = mw + quad * 4;
    #pragma unroll
    for (int c = 0; c < 4; ++c) {
        int f = 16 * c + col;
        #pragma unroll
        for (int r = 0; r < 4; ++r) {
            int m = mbase + r;
            if (m >= n_nodes) continue;
            float cm  = acc[c][r];
            float cs  = acc[c + 4][r];
            float miu = cm > 0.f ? cm : expm1f(cm);
            float sig = cs > 0.f ? cs : 0.f;
            float att = __expf(-sig);
            float uu  = miu * att;
            float vv  = sig * att * att;
            uv[(size_t)m * OUTF + f] = pack2bf(uu, vv);
        }
    }
}

// ---------------------------------------------------------------------------
// K2a: per-chunk sums over line-strided cnt.
// ---------------------------------------------------------------------------
__global__ __launch_bounds__(256) void chunk_sum(
    const int* __restrict__ cntS, int* __restrict__ chunkSum)
{
    __shared__ int buf[256];
    const int t   = threadIdx.x;
    const int idx = blockIdx.x * 256 + t;
    buf[t] = (idx < NNODES) ? cntS[(size_t)idx * CSTRIDE] : 0;
    __syncthreads();
    #pragma unroll
    for (int off = 128; off > 0; off >>= 1) {
        if (t < off) buf[t] += buf[t + off];
        __syncthreads();
    }
    if (t == 0) chunkSum[blockIdx.x] = buf[0];
}

// ---------------------------------------------------------------------------
// K2b: per-chunk exclusive scan + write start.
// ---------------------------------------------------------------------------
__global__ __launch_bounds__(256) void scan_write(
    const int* __restrict__ cntS, const int* __restrict__ chunkSum,
    int* __restrict__ start)
{
    __shared__ int pre[256];
    __shared__ int buf[256];
    const int t   = threadIdx.x;
    const int b   = blockIdx.x;
    const int idx = b * 256 + t;

    pre[t] = (t < NCHUNK && t < b) ? chunkSum[t] : 0;
    int val = (idx < NNODES) ? cntS[(size_t)idx * CSTRIDE] : 0;
    buf[t] = val;
    __syncthreads();

    #pragma unroll
    for (int off = 128; off > 0; off >>= 1) {
        if (t < off) pre[t] += pre[t + off];
        __syncthreads();
    }
    const int chunkOff = pre[0];

    #pragma unroll
    for (int off = 1; off < 256; off <<= 1) {
        int x = (t >= off) ? buf[t - off] : 0;
        __syncthreads();
        buf[t] += x;
        __syncthreads();
    }
    if (idx < NNODES)
        start[idx] = chunkOff + buf[t] - val;
    if (b == NCHUNK - 1 && t == 255) start[NNODES] = NEDGES;
}

// ---------------------------------------------------------------------------
// K3: place sorted tuples — no atomics. pos = start[dst] + rank[e].
// ---------------------------------------------------------------------------
__global__ __launch_bounds__(256) void place_kernel(
    const int* __restrict__ esrc,
    const int* __restrict__ edst,
    const float* __restrict__ a1,
    const float* __restrict__ a2,
    const int* __restrict__ rank,
    const int* __restrict__ start,
    int4* __restrict__ tup)
{
    const int base = blockIdx.x * 1024 + threadIdx.x;

    #pragma unroll
    for (int j = 0; j < 4; ++j) {
        int e = base + j * 256;
        if (e < NEDGES) {
            int d   = edst[e];
            int pos = start[d] + rank[e];
            tup[pos] = make_int4(esrc[e], __float_as_int(a1[e]),
                                 __float_as_int(a2[e]), 0);
        }
    }
}

// ---------------------------------------------------------------------------
// K4: one wave per dst node; lane = feature. Metadata streamed (sorted
// tuples), only uv gather random. Masked 16-wide batches — no serial tail:
// every load in a batch is independent (clamped index, zeroed weight).
// ---------------------------------------------------------------------------
__global__ __launch_bounds__(256) void gather_accum(
    const int4* __restrict__ tup,
    const int* __restrict__ start,
    const unsigned int* __restrict__ uv,
    float* __restrict__ outm,
    float* __restrict__ outs)
{
    const int n    = blockIdx.x * 4 + (threadIdx.x >> 6);
    const int lane = threadIdx.x & 63;
    if (n >= NNODES) return;

    const int beg = start[n];
    const int end = start[n + 1];

    float am = 0.f, as = 0.f;
    for (int i = beg; i < end; i += 16) {
        #pragma unroll
        for (int j = 0; j < 16; ++j) {
            int  idx   = i + j;
            bool valid = idx < end;          // wave-uniform
            int4 t = tup[valid ? idx : end - 1];
            unsigned int p = uv[(size_t)t.x * OUTF + lane];
            float w1 = valid ? __int_as_float(t.y) : 0.f;
            float w2 = valid ? __int_as_float(t.z) : 0.f;
            am = fmaf(w1, __uint_as_float(p << 16), am);
            as = fmaf(w2, __uint_as_float(p & 0xFFFF0000u), as);
        }
    }

    outm[(size_t)n * OUTF + lane] = am;
    outs[(size_t)n * OUTF + lane] = as;
}

extern "C" void kernel_launch(void* const* d_in, const int* in_sizes, int n_in,
                              void* d_out, int out_size, void* d_ws, size_t ws_size,
                              hipStream_t stream)
{
    const float* feat = (const float*)d_in[0];
    const int*   esrc = (const int*)d_in[1];
    const int*   edst = (const int*)d_in[2];
    const float* a1   = (const float*)d_in[3];
    const float* a2   = (const float*)d_in[4];
    const float* Wm   = (const float*)d_in[5];
    const float* Ws   = (const float*)d_in[6];

    float* outm = (float*)d_out;
    float* outs = outm + (size_t)NNODES * OUTF;

    // workspace layout (~33 MB)
    char* ws = (char*)d_ws;
    unsigned int*   uv  = (unsigned int*)ws;   ws += (size_t)NNODES * OUTF * 4;   // 12.8 MB
    unsigned short* BtG = (unsigned short*)ws; ws += (size_t)128 * INF * 2;       // 64 KB
    int4* tup     = (int4*)ws; ws += (size_t)NEDGES * 16;                          // 12.8 MB
    int* rank     = (int*)ws;  ws += (size_t)NEDGES * 4;                           // 3.2 MB
    int* cntS     = (int*)ws;  ws += (size_t)NNODES * CSTRIDE * 4;                 // 3.2 MB
    int* start    = (int*)ws;  ws += (size_t)(NNODES + 1) * 4;
    int* chunkSum = (int*)ws;

    hipMemsetAsync(cntS, 0, (size_t)NNODES * CSTRIDE * sizeof(int), stream);

    convert_hist<<<dim3(CVTBLK + HISTBLK), dim3(256), 0, stream>>>(
        Wm, Ws, BtG, edst, cntS, rank);

    gemm_mfma<<<dim3((NNODES + 63) / 64), dim3(256), 0, stream>>>(
        feat, BtG, uv, NNODES);

    chunk_sum<<<dim3(NCHUNK), dim3(256), 0, stream>>>(cntS, chunkSum);
    scan_write<<<dim3(NCHUNK), dim3(256), 0, stream>>>(cntS, chunkSum, start);
    place_kernel<<<dim3(HISTBLK), dim3(256), 0, stream>>>(
        esrc, edst, a1, a2, rank, start, tup);
    gather_accum<<<dim3((NNODES + 3) / 4), dim3(256), 0, stream>>>(
        tup, start, uv, outm, outs);
}

// Round 10
// 220.051 us; speedup vs baseline: 1.2263x; 1.2263x over previous
//
#include <hip/hip_runtime.h>
#include <math.h>

#define NNODES 50000
#define INF    256
#define OUTF   64
#define NEDGES 800000
#define NCHUNK 196            // ceil(50000/256)
#define CVTBLK 128            // blocks doing weight conversion in fused K1
#define HISTBLK ((NEDGES + 1023) / 1024)   // 782: 1024 edges/block, 4/thread
#define CSTRIDE 16            // one counter per 64B cacheline

typedef __attribute__((ext_vector_type(8))) short bf16x8;
typedef __attribute__((ext_vector_type(4))) float f32x4;

__device__ __forceinline__ unsigned short f2bf(float x) {
    unsigned int b = __float_as_uint(x);
    unsigned int r = b + 0x7FFF + ((b >> 16) & 1);   // RNE
    return (unsigned short)(r >> 16);
}

__device__ __forceinline__ unsigned int pack2bf(float lo, float hi) {
    return (unsigned int)f2bf(lo) | ((unsigned int)f2bf(hi) << 16);
}

// ---------------------------------------------------------------------------
// K1 (fused): blocks 0..127 transpose+convert weights; blocks 128..: dst
// histogram with line-strided counters, capturing each edge's RANK (atomic
// return value). 4 edges/thread for ILP.
// ---------------------------------------------------------------------------
__global__ __launch_bounds__(256) void convert_hist(
    const float* __restrict__ Wm, const float* __restrict__ Ws,
    unsigned short* __restrict__ BtG,
    const int* __restrict__ edst, int* __restrict__ cntS,
    int* __restrict__ rank)
{
    if (blockIdx.x < CVTBLK) {
        int n = blockIdx.x;          // 0..127
        int k = threadIdx.x;         // 0..255
        float val = (n < 64) ? Wm[(size_t)k * OUTF + n]
                             : Ws[(size_t)k * OUTF + (n - 64)];
        BtG[(size_t)n * INF + k] = f2bf(val);
    } else {
        int base = (blockIdx.x - CVTBLK) * 1024 + threadIdx.x;
        int d[4];
        bool ok[4];
        #pragma unroll
        for (int j = 0; j < 4; ++j) {
            int e = base + j * 256;
            ok[j] = (e < NEDGES);
            d[j]  = ok[j] ? edst[e] : 0;
        }
        int r[4];
        #pragma unroll
        for (int j = 0; j < 4; ++j)
            r[j] = ok[j] ? atomicAdd(&cntS[(size_t)d[j] * CSTRIDE], 1) : 0;
        #pragma unroll
        for (int j = 0; j < 4; ++j)
            if (ok[j]) rank[base + j * 256] = r[j];
    }
}

// ---------------------------------------------------------------------------
// K-GEMM: bf16 MFMA fused dual-GEMM + activation epilogue (round-8 proven
// LDS version — the round-9 LDS-free variant is unattributed +10 µs risk).
// ---------------------------------------------------------------------------
#define LDA 40   // padded k-stride (bf16 elems)
__global__ __launch_bounds__(256, 2) void gemm_mfma(
    const float* __restrict__ feat,
    const unsigned short* __restrict__ BtG,
    unsigned int* __restrict__ uv,
    int n_nodes)
{
    __shared__ __align__(16) unsigned short As[64 * LDA];
    __shared__ __align__(16) unsigned short Bs[128 * LDA];

    const int tid  = threadIdx.x;
    const int w    = tid >> 6;
    const int lane = tid & 63;
    const int quad = lane >> 4;
    const int col  = lane & 15;
    const int m0   = blockIdx.x * 64;

    f32x4 acc[8];
    #pragma unroll
    for (int c = 0; c < 8; ++c) acc[c] = (f32x4){0.f, 0.f, 0.f, 0.f};

    for (int kb = 0; kb < INF; kb += 32) {
        #pragma unroll
        for (int r = 0; r < 2; ++r) {
            int i   = tid + r * 256;
            int row = i >> 3;
            int q4  = i & 7;
            int m   = m0 + row;
            float4 val = make_float4(0.f, 0.f, 0.f, 0.f);
            if (m < n_nodes)
                val = *(const float4*)&feat[(size_t)m * INF + kb + q4 * 4];
            *(uint2*)&As[row * LDA + q4 * 4] =
                make_uint2(pack2bf(val.x, val.y), pack2bf(val.z, val.w));
        }
        #pragma unroll
        for (int r = 0; r < 2; ++r) {
            int i = tid + r * 256;
            int n = i >> 2;
            int q = i & 3;
            uint4 val = *(const uint4*)&BtG[(size_t)n * INF + kb + q * 8];
            *(uint4*)&Bs[n * LDA + q * 8] = val;
        }
        __syncthreads();

        bf16x8 af = *(const bf16x8*)&As[(16 * w + col) * LDA + quad * 8];
        #pragma unroll
        for (int c = 0; c < 8; ++c) {
            bf16x8 bf = *(const bf16x8*)&Bs[(16 * c + col) * LDA + quad * 8];
            acc[c] = __builtin_amdgcn_mfma_f32_16x16x32_bf16(af, bf, acc[c], 0, 0, 0);
        }
        __syncthreads();
    }

    const int mbase = m0 + 16 * w + quad * 4;
    #pragma unroll
    for (int c = 0; c < 4; ++c) {
        int f = 16 * c + col;
        #pragma unroll
        for (int r = 0; r < 4; ++r) {
            int m = mbase + r;
            if (m >= n_nodes) continue;
            float cm  = acc[c][r];
            float cs  = acc[c + 4][r];
            float miu = cm > 0.f ? cm : expm1f(cm);
            float sig = cs > 0.f ? cs : 0.f;
            float att = __expf(-sig);
            float uu  = miu * att;
            float vv  = sig * att * att;
            uv[(size_t)m * OUTF + f] = pack2bf(uu, vv);
        }
    }
}

// ---------------------------------------------------------------------------
// K2a: per-chunk sums over line-strided cnt.
// ---------------------------------------------------------------------------
__global__ __launch_bounds__(256) void chunk_sum(
    const int* __restrict__ cntS, int* __restrict__ chunkSum)
{
    __shared__ int buf[256];
    const int t   = threadIdx.x;
    const int idx = blockIdx.x * 256 + t;
    buf[t] = (idx < NNODES) ? cntS[(size_t)idx * CSTRIDE] : 0;
    __syncthreads();
    #pragma unroll
    for (int off = 128; off > 0; off >>= 1) {
        if (t < off) buf[t] += buf[t + off];
        __syncthreads();
    }
    if (t == 0) chunkSum[blockIdx.x] = buf[0];
}

// ---------------------------------------------------------------------------
// K2b: per-chunk exclusive scan + write start.
// ---------------------------------------------------------------------------
__global__ __launch_bounds__(256) void scan_write(
    const int* __restrict__ cntS, const int* __restrict__ chunkSum,
    int* __restrict__ start)
{
    __shared__ int pre[256];
    __shared__ int buf[256];
    const int t   = threadIdx.x;
    const int b   = blockIdx.x;
    const int idx = b * 256 + t;

    pre[t] = (t < NCHUNK && t < b) ? chunkSum[t] : 0;
    int val = (idx < NNODES) ? cntS[(size_t)idx * CSTRIDE] : 0;
    buf[t] = val;
    __syncthreads();

    #pragma unroll
    for (int off = 128; off > 0; off >>= 1) {
        if (t < off) pre[t] += pre[t + off];
        __syncthreads();
    }
    const int chunkOff = pre[0];

    #pragma unroll
    for (int off = 1; off < 256; off <<= 1) {
        int x = (t >= off) ? buf[t - off] : 0;
        __syncthreads();
        buf[t] += x;
        __syncthreads();
    }
    if (idx < NNODES)
        start[idx] = chunkOff + buf[t] - val;
    if (b == NCHUNK - 1 && t == 255) start[NNODES] = NEDGES;
}

// ---------------------------------------------------------------------------
// K3: place sorted 8B tuples {src, bf16(a1)|bf16(a2)<<16} — no atomics.
// pos = start[dst] + rank[e]. Halves the scattered-line write amplification
// vs 16B tuples (round-8 place WRITE_SIZE was 51.9 MB on a 12.8 MB buffer:
// 4 writers/line on different XCDs each dirty the line).
// ---------------------------------------------------------------------------
__global__ __launch_bounds__(256) void place_kernel(
    const int* __restrict__ esrc,
    const int* __restrict__ edst,
    const float* __restrict__ a1,
    const float* __restrict__ a2,
    const int* __restrict__ rank,
    const int* __restrict__ start,
    uint2* __restrict__ tup)
{
    const int base = blockIdx.x * 1024 + threadIdx.x;

    #pragma unroll
    for (int j = 0; j < 4; ++j) {
        int e = base + j * 256;
        if (e < NEDGES) {
            int d   = edst[e];
            int pos = start[d] + rank[e];
            tup[pos] = make_uint2((unsigned int)esrc[e],
                                  pack2bf(a1[e], a2[e]));
        }
    }
}

// ---------------------------------------------------------------------------
// K4: one wave per dst node; lane = feature. Round-8 proven structure:
// 8-edge unroll with UNIFORM tup addresses (scalar-load promotion -> 8
// tuples in flight via SGPRs) + serial tail. Only uv gather is random.
// ---------------------------------------------------------------------------
__global__ __launch_bounds__(256) void gather_accum(
    const uint2* __restrict__ tup,
    const int* __restrict__ start,
    const unsigned int* __restrict__ uv,
    float* __restrict__ outm,
    float* __restrict__ outs)
{
    const int n    = blockIdx.x * 4 + (threadIdx.x >> 6);
    const int lane = threadIdx.x & 63;
    if (n >= NNODES) return;

    const int beg = start[n];
    const int end = start[n + 1];

    float am = 0.f, as = 0.f;
    int i = beg;
    for (; i + 8 <= end; i += 8) {
        #pragma unroll
        for (int j = 0; j < 8; ++j) {
            uint2 t = tup[i + j];
            unsigned int p = uv[(size_t)t.x * OUTF + lane];
            am = fmaf(__uint_as_float(t.y << 16),
                      __uint_as_float(p << 16), am);
            as = fmaf(__uint_as_float(t.y & 0xFFFF0000u),
                      __uint_as_float(p & 0xFFFF0000u), as);
        }
    }
    for (; i < end; ++i) {
        uint2 t = tup[i];
        unsigned int p = uv[(size_t)t.x * OUTF + lane];
        am = fmaf(__uint_as_float(t.y << 16),
                  __uint_as_float(p << 16), am);
        as = fmaf(__uint_as_float(t.y & 0xFFFF0000u),
                  __uint_as_float(p & 0xFFFF0000u), as);
    }

    outm[(size_t)n * OUTF + lane] = am;
    outs[(size_t)n * OUTF + lane] = as;
}

extern "C" void kernel_launch(void* const* d_in, const int* in_sizes, int n_in,
                              void* d_out, int out_size, void* d_ws, size_t ws_size,
                              hipStream_t stream)
{
    const float* feat = (const float*)d_in[0];
    const int*   esrc = (const int*)d_in[1];
    const int*   edst = (const int*)d_in[2];
    const float* a1   = (const float*)d_in[3];
    const float* a2   = (const float*)d_in[4];
    const float* Wm   = (const float*)d_in[5];
    const float* Ws   = (const float*)d_in[6];

    float* outm = (float*)d_out;
    float* outs = outm + (size_t)NNODES * OUTF;

    // workspace layout (~26 MB)
    char* ws = (char*)d_ws;
    unsigned int*   uv  = (unsigned int*)ws;   ws += (size_t)NNODES * OUTF * 4;   // 12.8 MB
    unsigned short* BtG = (unsigned short*)ws; ws += (size_t)128 * INF * 2;       // 64 KB
    uint2* tup    = (uint2*)ws; ws += (size_t)NEDGES * 8;                          // 6.4 MB
    int* rank     = (int*)ws;  ws += (size_t)NEDGES * 4;                           // 3.2 MB
    int* cntS     = (int*)ws;  ws += (size_t)NNODES * CSTRIDE * 4;                 // 3.2 MB
    int* start    = (int*)ws;  ws += (size_t)(NNODES + 1) * 4;
    int* chunkSum = (int*)ws;

    hipMemsetAsync(cntS, 0, (size_t)NNODES * CSTRIDE * sizeof(int), stream);

    convert_hist<<<dim3(CVTBLK + HISTBLK), dim3(256), 0, stream>>>(
        Wm, Ws, BtG, edst, cntS, rank);

    gemm_mfma<<<dim3((NNODES + 63) / 64), dim3(256), 0, stream>>>(
        feat, BtG, uv, NNODES);

    chunk_sum<<<dim3(NCHUNK), dim3(256), 0, stream>>>(cntS, chunkSum);
    scan_write<<<dim3(NCHUNK), dim3(256), 0, stream>>>(cntS, chunkSum, start);
    place_kernel<<<dim3(HISTBLK), dim3(256), 0, stream>>>(
        esrc, edst, a1, a2, rank, start, tup);
    gather_accum<<<dim3((NNODES + 3) / 4), dim3(256), 0, stream>>>(
        tup, start, uv, outm, outs);
}

// Round 11
// 218.458 us; speedup vs baseline: 1.2353x; 1.0073x over previous
//
#include <hip/hip_runtime.h>
#include <math.h>

#define NNODES 50000
#define INF    256
#define OUTF   64
#define NEDGES 800000
#define NCHUNK 196            // ceil(50000/256)
#define GEMMB  782            // ceil(50000/64) gemm blocks
#define HISTB  782            // 1024 edges/block, 4/thread
#define CSTRIDE 16            // one counter per 64B cacheline

typedef __attribute__((ext_vector_type(8))) short bf16x8;
typedef __attribute__((ext_vector_type(4))) float f32x4;

__device__ __forceinline__ unsigned short f2bf(float x) {
    unsigned int b = __float_as_uint(x);
    unsigned int r = b + 0x7FFF + ((b >> 16) & 1);   // RNE
    return (unsigned short)(r >> 16);
}

__device__ __forceinline__ unsigned int pack2bf(float lo, float hi) {
    return (unsigned int)f2bf(lo) | ((unsigned int)f2bf(hi) << 16);
}

// ---------------------------------------------------------------------------
// K0: transpose+convert weights to bf16 BtG[n][k] (tiny, 128 blocks).
// ---------------------------------------------------------------------------
__global__ __launch_bounds__(256) void convert_B(
    const float* __restrict__ Wm, const float* __restrict__ Ws,
    unsigned short* __restrict__ BtG)
{
    int n = blockIdx.x;          // 0..127
    int k = threadIdx.x;         // 0..255
    float val = (n < 64) ? Wm[(size_t)k * OUTF + n]
                         : Ws[(size_t)k * OUTF + (n - 64)];
    BtG[(size_t)n * INF + k] = f2bf(val);
}

// ---------------------------------------------------------------------------
// K1 (fused): blocks 0..GEMMB-1: bf16 MFMA dual-GEMM + activation epilogue
// (round-8 proven body). Blocks GEMMB..: dst histogram with line-strided
// counters, capturing each edge's RANK. The two parts are data-independent;
// co-residency overlaps the MFMA/LDS pipe (gemm) with the atomic/latency
// pipe (hist) — m114: co-scheduled waves run at max, not sum.
// ---------------------------------------------------------------------------
#define LDA 40   // padded k-stride (bf16 elems)
__global__ __launch_bounds__(256, 2) void gemm_hist(
    const float* __restrict__ feat,
    const unsigned short* __restrict__ BtG,
    unsigned int* __restrict__ uv,
    const int* __restrict__ edst,
    int* __restrict__ cntS,
    int* __restrict__ rank,
    int n_nodes)
{
    if (blockIdx.x < GEMMB) {
        __shared__ __align__(16) unsigned short As[64 * LDA];
        __shared__ __align__(16) unsigned short Bs[128 * LDA];

        const int tid  = threadIdx.x;
        const int w    = tid >> 6;
        const int lane = tid & 63;
        const int quad = lane >> 4;
        const int col  = lane & 15;
        const int m0   = blockIdx.x * 64;

        f32x4 acc[8];
        #pragma unroll
        for (int c = 0; c < 8; ++c) acc[c] = (f32x4){0.f, 0.f, 0.f, 0.f};

        for (int kb = 0; kb < INF; kb += 32) {
            #pragma unroll
            for (int r = 0; r < 2; ++r) {
                int i   = tid + r * 256;
                int row = i >> 3;
                int q4  = i & 7;
                int m   = m0 + row;
                float4 val = make_float4(0.f, 0.f, 0.f, 0.f);
                if (m < n_nodes)
                    val = *(const float4*)&feat[(size_t)m * INF + kb + q4 * 4];
                *(uint2*)&As[row * LDA + q4 * 4] =
                    make_uint2(pack2bf(val.x, val.y), pack2bf(val.z, val.w));
            }
            #pragma unroll
            for (int r = 0; r < 2; ++r) {
                int i = tid + r * 256;
                int n = i >> 2;
                int q = i & 3;
                uint4 val = *(const uint4*)&BtG[(size_t)n * INF + kb + q * 8];
                *(uint4*)&Bs[n * LDA + q * 8] = val;
            }
            __syncthreads();

            bf16x8 af = *(const bf16x8*)&As[(16 * w + col) * LDA + quad * 8];
            #pragma unroll
            for (int c = 0; c < 8; ++c) {
                bf16x8 bf = *(const bf16x8*)&Bs[(16 * c + col) * LDA + quad * 8];
                acc[c] = __builtin_amdgcn_mfma_f32_16x16x32_bf16(af, bf, acc[c], 0, 0, 0);
            }
            __syncthreads();
        }

        const int mbase = m0 + 16 * w + quad * 4;
        #pragma unroll
        for (int c = 0; c < 4; ++c) {
            int f = 16 * c + col;
            #pragma unroll
            for (int r = 0; r < 4; ++r) {
                int m = mbase + r;
                if (m >= n_nodes) continue;
                float cm  = acc[c][r];
                float cs  = acc[c + 4][r];
                float miu = cm > 0.f ? cm : expm1f(cm);
                float sig = cs > 0.f ? cs : 0.f;
                float att = __expf(-sig);
                float uu  = miu * att;
                float vv  = sig * att * att;
                uv[(size_t)m * OUTF + f] = pack2bf(uu, vv);
            }
        }
    } else {
        int base = (blockIdx.x - GEMMB) * 1024 + threadIdx.x;
        int d[4];
        bool ok[4];
        #pragma unroll
        for (int j = 0; j < 4; ++j) {
            int e = base + j * 256;
            ok[j] = (e < NEDGES);
            d[j]  = ok[j] ? edst[e] : 0;
        }
        int r[4];
        #pragma unroll
        for (int j = 0; j < 4; ++j)
            r[j] = ok[j] ? atomicAdd(&cntS[(size_t)d[j] * CSTRIDE], 1) : 0;
        #pragma unroll
        for (int j = 0; j < 4; ++j)
            if (ok[j]) rank[base + j * 256] = r[j];
    }
}

// ---------------------------------------------------------------------------
// K2a: per-chunk sums over line-strided cnt.
// ---------------------------------------------------------------------------
__global__ __launch_bounds__(256) void chunk_sum(
    const int* __restrict__ cntS, int* __restrict__ chunkSum)
{
    __shared__ int buf[256];
    const int t   = threadIdx.x;
    const int idx = blockIdx.x * 256 + t;
    buf[t] = (idx < NNODES) ? cntS[(size_t)idx * CSTRIDE] : 0;
    __syncthreads();
    #pragma unroll
    for (int off = 128; off > 0; off >>= 1) {
        if (t < off) buf[t] += buf[t + off];
        __syncthreads();
    }
    if (t == 0) chunkSum[blockIdx.x] = buf[0];
}

// ---------------------------------------------------------------------------
// K2b: per-chunk exclusive scan + write start.
// ---------------------------------------------------------------------------
__global__ __launch_bounds__(256) void scan_write(
    const int* __restrict__ cntS, const int* __restrict__ chunkSum,
    int* __restrict__ start)
{
    __shared__ int pre[256];
    __shared__ int buf[256];
    const int t   = threadIdx.x;
    const int b   = blockIdx.x;
    const int idx = b * 256 + t;

    pre[t] = (t < NCHUNK && t < b) ? chunkSum[t] : 0;
    int val = (idx < NNODES) ? cntS[(size_t)idx * CSTRIDE] : 0;
    buf[t] = val;
    __syncthreads();

    #pragma unroll
    for (int off = 128; off > 0; off >>= 1) {
        if (t < off) pre[t] += pre[t + off];
        __syncthreads();
    }
    const int chunkOff = pre[0];

    #pragma unroll
    for (int off = 1; off < 256; off <<= 1) {
        int x = (t >= off) ? buf[t - off] : 0;
        __syncthreads();
        buf[t] += x;
        __syncthreads();
    }
    if (idx < NNODES)
        start[idx] = chunkOff + buf[t] - val;
    if (b == NCHUNK - 1 && t == 255) start[NNODES] = NEDGES;
}

// ---------------------------------------------------------------------------
// K3: place sorted 8B tuples {src, bf16(a1)|bf16(a2)<<16} — no atomics.
// ---------------------------------------------------------------------------
__global__ __launch_bounds__(256) void place_kernel(
    const int* __restrict__ esrc,
    const int* __restrict__ edst,
    const float* __restrict__ a1,
    const float* __restrict__ a2,
    const int* __restrict__ rank,
    const int* __restrict__ start,
    uint2* __restrict__ tup)
{
    const int base = blockIdx.x * 1024 + threadIdx.x;

    #pragma unroll
    for (int j = 0; j < 4; ++j) {
        int e = base + j * 256;
        if (e < NEDGES) {
            int d   = edst[e];
            int pos = start[d] + rank[e];
            tup[pos] = make_uint2((unsigned int)esrc[e],
                                  pack2bf(a1[e], a2[e]));
        }
    }
}

// ---------------------------------------------------------------------------
// K4: one wave per dst node; lane = feature. 8-edge unroll, uniform tup
// addresses (scalar-load promotion), serial tail. Nontemporal output
// stores: outputs are never re-read — keep uv resident in L2 instead.
// ---------------------------------------------------------------------------
__global__ __launch_bounds__(256) void gather_accum(
    const uint2* __restrict__ tup,
    const int* __restrict__ start,
    const unsigned int* __restrict__ uv,
    float* __restrict__ outm,
    float* __restrict__ outs)
{
    const int n    = blockIdx.x * 4 + (threadIdx.x >> 6);
    const int lane = threadIdx.x & 63;
    if (n >= NNODES) return;

    const int beg = start[n];
    const int end = start[n + 1];

    float am = 0.f, as = 0.f;
    int i = beg;
    for (; i + 8 <= end; i += 8) {
        #pragma unroll
        for (int j = 0; j < 8; ++j) {
            uint2 t = tup[i + j];
            unsigned int p = uv[(size_t)t.x * OUTF + lane];
            am = fmaf(__uint_as_float(t.y << 16),
                      __uint_as_float(p << 16), am);
            as = fmaf(__uint_as_float(t.y & 0xFFFF0000u),
                      __uint_as_float(p & 0xFFFF0000u), as);
        }
    }
    for (; i < end; ++i) {
        uint2 t = tup[i];
        unsigned int p = uv[(size_t)t.x * OUTF + lane];
        am = fmaf(__uint_as_float(t.y << 16),
                  __uint_as_float(p << 16), am);
        as = fmaf(__uint_as_float(t.y & 0xFFFF0000u),
                  __uint_as_float(p & 0xFFFF0000u), as);
    }

    __builtin_nontemporal_store(am, &outm[(size_t)n * OUTF + lane]);
    __builtin_nontemporal_store(as, &outs[(size_t)n * OUTF + lane]);
}

extern "C" void kernel_launch(void* const* d_in, const int* in_sizes, int n_in,
                              void* d_out, int out_size, void* d_ws, size_t ws_size,
                              hipStream_t stream)
{
    const float* feat = (const float*)d_in[0];
    const int*   esrc = (const int*)d_in[1];
    const int*   edst = (const int*)d_in[2];
    const float* a1   = (const float*)d_in[3];
    const float* a2   = (const float*)d_in[4];
    const float* Wm   = (const float*)d_in[5];
    const float* Ws   = (const float*)d_in[6];

    float* outm = (float*)d_out;
    float* outs = outm + (size_t)NNODES * OUTF;

    // workspace layout (~26 MB)
    char* ws = (char*)d_ws;
    unsigned int*   uv  = (unsigned int*)ws;   ws += (size_t)NNODES * OUTF * 4;   // 12.8 MB
    unsigned short* BtG = (unsigned short*)ws; ws += (size_t)128 * INF * 2;       // 64 KB
    uint2* tup    = (uint2*)ws; ws += (size_t)NEDGES * 8;                          // 6.4 MB
    int* rank     = (int*)ws;  ws += (size_t)NEDGES * 4;                           // 3.2 MB
    int* cntS     = (int*)ws;  ws += (size_t)NNODES * CSTRIDE * 4;                 // 3.2 MB
    int* start    = (int*)ws;  ws += (size_t)(NNODES + 1) * 4;
    int* chunkSum = (int*)ws;

    hipMemsetAsync(cntS, 0, (size_t)NNODES * CSTRIDE * sizeof(int), stream);

    convert_B<<<dim3(128), dim3(256), 0, stream>>>(Wm, Ws, BtG);

    gemm_hist<<<dim3(GEMMB + HISTB), dim3(256), 0, stream>>>(
        feat, BtG, uv, edst, cntS, rank, NNODES);

    chunk_sum<<<dim3(NCHUNK), dim3(256), 0, stream>>>(cntS, chunkSum);
    scan_write<<<dim3(NCHUNK), dim3(256), 0, stream>>>(cntS, chunkSum, start);
    place_kernel<<<dim3(HISTB), dim3(256), 0, stream>>>(
        esrc, edst, a1, a2, rank, start, tup);
    gather_accum<<<dim3((NNODES + 3) / 4), dim3(256), 0, stream>>>(
        tup, start, uv, outm, outs);
}